// Round 8
// baseline (159.129 us; speedup 1.0000x reference)
//
#include <hip/hip_runtime.h>

// VQ-VAE quantization. x: [32,64,64,64] fp32, emb: [1024,64] fp32
#define BATCH   32
#define CCH     64
#define HW      4096
#define NPIX    (BATCH * HW)        // 131072
#define KCODES  1024
#define NELEM   (NPIX * CCH)        // 8388608
#define MB      256                 // pixels per block (32 per wave, 2 row-tiles, 8 waves)
#define CK      128                 // codes per LDS chunk (8 chunks, 2x32KB dbuf -> 2 blocks/CU)
#define NBLK    (NPIX / MB)         // 512
#define MARGIN_Q 5u                 // ambiguity margin, 1/4096 units (err<=2 w/ LL term; 2*err+1)
#define QSCALE   4096.0f            // distance quantization scale
#define QBASE    1048576.0f         // 2^20 baseline; uf stays in (0, 2^22)

typedef _Float16 f16;
typedef __attribute__((ext_vector_type(8))) _Float16 f16x8;
typedef __attribute__((ext_vector_type(4))) float    f32x4;

static __device__ __forceinline__ f32x4 mfma16(f16x8 a, f16x8 b, f32x4 c) {
    return __builtin_amdgcn_mfma_f32_16x16x32_f16(a, b, c, 0, 0, 0);
}

static __device__ __forceinline__ void dma16(void* lds, const void* g) {
    __builtin_amdgcn_global_load_lds(
        (const __attribute__((address_space(1))) unsigned int*)g,
        (__attribute__((address_space(3))) unsigned int*)lds, 16, 0, 0);
}

// median of 3 u32 (v_med3_u32)
static __device__ __forceinline__ unsigned med3u(unsigned a, unsigned b, unsigned c) {
    unsigned d;
    asm("v_med3_u32 %0, %1, %2, %3" : "=v"(d) : "v"(a), "v"(b), "v"(c));
    return d;
}

// ws layout (bytes):
//   [0] f32 loss acc   [8] u32 done-counter (same 64B line as acc)
//   [256..4352)       eeb[k] = 4096*||e_k||^2 + 2^20  (1024 f32)
//   [8192..139264)    cbH swizzled fp16-hi codebook (row r granule g at r*64 + 8*(g^(r&7)))
//   [139264..270336)  cbL fp16-lo, same swizzle
#define WS_EEB_F   64
#define WS_CBH_B   8192
#define WS_CBL_B   139264

__global__ __launch_bounds__(256) void vq_prep(
    const float* __restrict__ emb, float* __restrict__ wsf,
    unsigned* __restrict__ wsu, f16* __restrict__ cbH, f16* __restrict__ cbL,
    float* __restrict__ eeb_g)
{
    const int t   = threadIdx.x;
    const int gid = blockIdx.x * 256 + t;        // 0..8191 granules
    const int row = gid >> 3, gi = gid & 7;
    if (gid == 0) { wsf[0] = 0.f; wsu[2] = 0u; }
    const float* src = emb + (size_t)row * CCH + gi * 8;
    float4 v0 = *(const float4*)(src);
    float4 v1 = *(const float4*)(src + 4);
    float vv[8] = {v0.x, v0.y, v0.z, v0.w, v1.x, v1.y, v1.z, v1.w};
    f16x8 h, l;
    float s = 0.f;
#pragma unroll
    for (int j = 0; j < 8; ++j) {
        f16 hh = (f16)vv[j];
        h[j] = hh;
        l[j] = (f16)(vv[j] - (float)hh);
        s = fmaf(vv[j], vv[j], s);
    }
    const int off = row * 64 + 8 * (gi ^ (row & 7));
    *(f16x8*)(cbH + off) = h;
    *(f16x8*)(cbL + off) = l;
    // ||e||^2: reduce across the 8 granule-threads of this row (adjacent lanes)
    s += __shfl_xor(s, 1, 64);
    s += __shfl_xor(s, 2, 64);
    s += __shfl_xor(s, 4, 64);
    if (gi == 0) eeb_g[row] = fmaf(s, QSCALE, QBASE);
}

// 8 waves x 32 pixels, 2 blocks/CU (L2-resident codebook).
// Full H/L product (8 MFMAs incl. LL term) -> distance err <= ~2 units.
// Top-3 tracking: ambiguous pixels with gap3 >= M need only an exact {b1,b2}
// pair-compare (1 thread each); full 1024-code rescan only when gap3 < M (rare).
__global__ __launch_bounds__(512, 4) void vq_main(
    const float* __restrict__ x,
    const float* __restrict__ emb,
    const f16* __restrict__ cbH, const f16* __restrict__ cbL,
    const float* __restrict__ eeb_g,
    float* __restrict__ o, float* __restrict__ idx_out,
    float* __restrict__ acc, unsigned* __restrict__ done,
    float* __restrict__ loss)
{
    __shared__ __align__(16) char smem[65536];      // 2 x (16K H | 16K L)
    __shared__ float eebl[2][CK];
    __shared__ unsigned bu1[MB], bu2[MB], bu3[MB];
    __shared__ float wred[8];
    __shared__ unsigned short plist[MB], flist[MB];
    __shared__ int np, nf;
    __shared__ __align__(16) float zsh[CCH];
    __shared__ double rbd[8];
    __shared__ int rbi[8];

    const int t    = threadIdx.x;
    const int lane = t & 63;
    const int w    = t >> 6;               // 0..7
    const int col  = lane & 15;
    const int quad = lane >> 4;
    const int c7   = col & 7;
    const int sw0  = 8 * (quad ^ c7);      // swizzled granule offset, chans 0..31
    const int sw1  = sw0 ^ 32;             // chans 32..63
    const int n0   = blockIdx.x * MB;
    const int b    = n0 >> 12;
    const int p0   = n0 & 4095;
    const float* xb = x + (size_t)b * (CCH * HW) + p0;

    // wave w stages its 2KB slice of each 16KB H/L region
    auto stage = [&](int chunk, int bufi) {
        const int k0 = chunk * CK;
        char* lb = smem + bufi * 32768;
        const char* gH = (const char*)cbH + (size_t)k0 * 128 + w * 2048 + lane * 16;
        const char* gL = (const char*)cbL + (size_t)k0 * 128 + w * 2048 + lane * 16;
        char* lH = lb + w * 2048;
        char* lL = lb + 16384 + w * 2048;
        dma16(lH,        gH);
        dma16(lH + 1024, gH + 1024);
        dma16(lL,        gL);
        dma16(lL + 1024, gL + 1024);
        if (t < CK) eebl[bufi][t] = eeb_g[k0 + t];
    };

    stage(0, 0);    // DMA in flight while we build A fragments

    // ---- A fragments straight from global (MFMA A-layout, no LDS trip) ----
    // lane holds pixel (w*32 + rt*16 + col), chans kc*32 + quad*8 + j
    f16x8 aH[2][2], aL[2][2];
#pragma unroll
    for (int rt = 0; rt < 2; ++rt) {
        const int pp = w * 32 + rt * 16 + col;
#pragma unroll
        for (int kc = 0; kc < 2; ++kc) {
            f16x8 h, l;
#pragma unroll
            for (int j = 0; j < 8; ++j) {
                const int c = kc * 32 + quad * 8 + j;
                float zs = -2.0f * xb[(size_t)c * HW + pp];
                f16 hh = (f16)zs;
                h[j] = hh;
                l[j] = (f16)(zs - (float)hh);
            }
            aH[rt][kc] = h;
            aL[rt][kc] = l;
        }
    }

    unsigned best[8], best2[8], best3[8];
#pragma unroll
    for (int s = 0; s < 8; ++s) {
        best[s] = 0xFFFFFFFFu; best2[s] = 0xFFFFFFFFu; best3[s] = 0xFFFFFFFFu;
    }

    const f32x4 zero4 = {0.f, 0.f, 0.f, 0.f};   // persistent C-init quad

    for (int chunk = 0; chunk < KCODES / CK; ++chunk) {
        const int cur = chunk & 1;
        __syncthreads();                        // chunk's DMA visible to all
        if (chunk + 1 < KCODES / CK) stage(chunk + 1, cur ^ 1);

        const f16* bufH = (const f16*)(smem + cur * 32768);
        const f16* bufL = bufH + 8192;          // +16384 bytes
        const int k0 = chunk * CK;

#pragma unroll
        for (int tile = 0; tile < CK / 16; ++tile) {
            const f16* bh = bufH + (tile * 16 + col) * 64;
            const f16* bl = bufL + (tile * 16 + col) * 64;
            f16x8 bH0 = *(const f16x8*)(bh + sw0);
            f16x8 bH1 = *(const f16x8*)(bh + sw1);
            f16x8 bL0 = *(const f16x8*)(bl + sw0);
            f16x8 bL1 = *(const f16x8*)(bl + sw1);
            const float eebc = eebl[cur][tile * 16 + col];
            const unsigned kb = (unsigned)(k0 + tile * 16 + col);
#pragma unroll
            for (int rt = 0; rt < 2; ++rt) {
                // full H/L product: two independent 4-deep MFMA chains (incl. LL)
                f32x4 u = mfma16(aH[rt][0], bH0, zero4);
                f32x4 v = mfma16(aH[rt][1], bH1, zero4);
                u = mfma16(aL[rt][0], bH0, u);
                v = mfma16(aL[rt][1], bH1, v);
                u = mfma16(aH[rt][0], bL0, u);
                v = mfma16(aH[rt][1], bL1, v);
                u = mfma16(aL[rt][0], bL0, u);
                v = mfma16(aL[rt][1], bL1, v);
#pragma unroll
                for (int r = 0; r < 4; ++r) {
                    float uf = fmaf(u[r] + v[r], QSCALE, eebc);   // in (0, 2^22)
                    unsigned pk = (((unsigned)uf) << 10) | kb;
                    const int s = rt * 4 + r;
                    const unsigned b1 = best[s], b2 = best2[s];
                    best3[s] = med3u(b2, best3[s], pk);  // 3rd-best insert (uses old b2)
                    best2[s] = med3u(b1, b2, pk);        // 2nd-best insert
                    best[s]  = min(b1, pk);
                }
            }
        }
    }

    // ---- cross-lane sorted-top-3 merge over the 16 code-columns ----
#pragma unroll
    for (int d = 1; d < 16; d <<= 1) {
#pragma unroll
        for (int s = 0; s < 8; ++s) {
            unsigned o1 = __shfl_xor(best[s],  d, 64);
            unsigned o2 = __shfl_xor(best2[s], d, 64);
            unsigned o3 = __shfl_xor(best3[s], d, 64);
            unsigned m1 = max(best[s], o1);
            unsigned n2 = min(best2[s], o2);
            unsigned x2 = max(best2[s], o2);
            unsigned n3 = min(best3[s], o3);
            best3[s] = min(min(max(m1, n2), x2), n3);
            best2[s] = min(m1, n2);
            best[s]  = min(best[s], o1);
        }
    }
    if (t == 0) { np = 0; nf = 0; }
    if (col == 0) {
#pragma unroll
        for (int rt = 0; rt < 2; ++rt)
#pragma unroll
            for (int r = 0; r < 4; ++r) {
                const int pl = w * 32 + rt * 16 + quad * 4 + r;   // C/D row map
                bu1[pl] = best[rt * 4 + r];
                bu2[pl] = best2[rt * 4 + r];
                bu3[pl] = best3[rt * 4 + r];
            }
    }
    __syncthreads();

    // ---- classify ambiguous pixels ----
    if (t < MB) {
        const unsigned q1 = bu1[t] >> 10;
        if ((bu2[t] >> 10) - q1 < MARGIN_Q) {
            if ((bu3[t] >> 10) - q1 < MARGIN_Q) {
                flist[atomicAdd(&nf, 1)] = (unsigned short)t;   // rare: full rescan
            } else {
                plist[atomicAdd(&np, 1)] = (unsigned short)t;   // common: pair-compare
            }
        }
    }
    __syncthreads();

    // ---- pair path: one thread per pixel, exact fp64 over {b1, b2} only ----
    if (t < np) {
        const int pix = plist[t];
        const unsigned k1 = bu1[pix] & 1023u, k2 = bu2[pix] & 1023u;
        const float* e1 = emb + (size_t)k1 * CCH;
        const float* e2 = emb + (size_t)k2 * CCH;
        const float* xp = xb + pix;
        double d1 = 0.0, d2 = 0.0;
#pragma unroll 1
        for (int c = 0; c < CCH; c += 4) {
            float4 a4 = *(const float4*)(e1 + c);
            float4 b4 = *(const float4*)(e2 + c);
            float xv0 = xp[(size_t)(c + 0) * HW];
            float xv1 = xp[(size_t)(c + 1) * HW];
            float xv2 = xp[(size_t)(c + 2) * HW];
            float xv3 = xp[(size_t)(c + 3) * HW];
            double ta0 = (double)xv0 - (double)a4.x, tb0 = (double)xv0 - (double)b4.x;
            double ta1 = (double)xv1 - (double)a4.y, tb1 = (double)xv1 - (double)b4.y;
            double ta2 = (double)xv2 - (double)a4.z, tb2 = (double)xv2 - (double)b4.z;
            double ta3 = (double)xv3 - (double)a4.w, tb3 = (double)xv3 - (double)b4.w;
            d1 = fma(ta0, ta0, fma(ta1, ta1, fma(ta2, ta2, fma(ta3, ta3, d1))));
            d2 = fma(tb0, tb0, fma(tb1, tb1, fma(tb2, tb2, fma(tb3, tb3, d2))));
        }
        const unsigned kw = (d2 < d1 || (d2 == d1 && k2 < k1)) ? k2 : k1;
        bu1[pix] = kw;
    }

    // ---- full-rescan path (rare): block-cooperative exact fp64 over 1024 codes ----
    const int nfl = nf;
    for (int i = 0; i < nfl; ++i) {
        const int pix = flist[i];
        __syncthreads();
        if (t < CCH) zsh[t] = xb[(size_t)t * HW + pix];
        __syncthreads();
        double bd = 1e300; int bi = KCODES;
#pragma unroll 1
        for (int j = 0; j < 2; ++j) {
            const int k = t + j * 512;
            const float4* er4 = (const float4*)(emb + (size_t)k * CCH);
            const float4* zs4 = (const float4*)zsh;
            double d = 0.0;
#pragma unroll 1
            for (int c = 0; c < 16; ++c) {
                float4 ev = er4[c];
                float4 zv = zs4[c];
                double t0 = (double)zv.x - (double)ev.x;
                double t1 = (double)zv.y - (double)ev.y;
                double t2 = (double)zv.z - (double)ev.z;
                double t3 = (double)zv.w - (double)ev.w;
                d = fma(t0, t0, fma(t1, t1, fma(t2, t2, fma(t3, t3, d))));
            }
            if (d < bd) { bd = d; bi = k; }     // k ascending: strict < keeps lowest idx
        }
#pragma unroll 1
        for (int dlt = 1; dlt < 64; dlt <<= 1) {
            double od = __shfl_xor(bd, dlt, 64);
            int    oi = __shfl_xor(bi, dlt, 64);
            if (od < bd || (od == bd && oi < bi)) { bd = od; bi = oi; }
        }
        if (lane == 0) { rbd[w] = bd; rbi[w] = bi; }
        __syncthreads();
        if (t == 0) {
            double fb = rbd[0]; int fi = rbi[0];
            for (int q = 1; q < 8; ++q)
                if (rbd[q] < fb || (rbd[q] == fb && rbi[q] < fi)) { fb = rbd[q]; fi = rbi[q]; }
            bu1[pix] = (unsigned)fi;
        }
    }
    __syncthreads();   // pair/full bu1 updates visible to epilogue

    // ---- epilogue: 512 threads over 256 pixels x 64 chans (half each) ----
    const int pix  = t & 255;
    const int half = t >> 8;               // 0: chans 0..31, 1: chans 32..63
    const unsigned bidx = bu1[pix] & 1023u;
    if (half == 0) {
        idx_out[n0 + pix] = (float)bidx;
    }
    float ss = 0.f;
    {
        const float4* er4 = (const float4*)(emb + (size_t)bidx * CCH) + half * 8;
        const float* xbt = xb + pix;
        float* ob = o + (size_t)b * (CCH * HW) + p0 + pix;
#pragma unroll
        for (int i = 0; i < 8; ++i) {
            float4 ev = er4[i];
            float evv[4] = {ev.x, ev.y, ev.z, ev.w};
#pragma unroll
            for (int q = 0; q < 4; ++q) {
                const int c = half * 32 + i * 4 + q;
                float xv = xbt[(size_t)c * HW];
                float e  = evv[q];
                ob[(size_t)c * HW] = xv + (e - xv);
                float d = xv - e;
                ss = fmaf(d, d, ss);
            }
        }
    }
    for (int off = 32; off; off >>= 1) ss += __shfl_down(ss, off, 64);
    if (lane == 0) wred[w] = ss;
    __syncthreads();
    if (t == 0) {
        float s2 = 0.f;
#pragma unroll
        for (int q = 0; q < 8; ++q) s2 += wred[q];
        // fused finalization, fence-free (R7-proven):
        float old = atomicAdd(acc, s2);               // device-scope, returns -> vmcnt wait
        asm volatile("" : : "v"(old));                // consume: acc-add applied at L2 here
        unsigned prev = atomicAdd(done, 1u);          // same 64B line as acc -> serialized
        if (prev == (unsigned)(NBLK - 1)) {
            float a = atomicAdd(acc, 0.0f);           // complete sum
            *loss = 1.25f * a * (1.0f / (float)NELEM);
        }
    }
}

extern "C" void kernel_launch(void* const* d_in, const int* in_sizes, int n_in,
                              void* d_out, int out_size, void* d_ws, size_t ws_size,
                              hipStream_t stream) {
    const float* x   = (const float*)d_in[0];
    const float* emb = (const float*)d_in[1];
    float*    out = (float*)d_out;
    float*    wsf = (float*)d_ws;
    unsigned* wsu = (unsigned*)d_ws;
    char*     wsb = (char*)d_ws;

    float* o_out    = out;
    float* loss_out = out + NELEM;
    float* idx_out  = out + NELEM + 1;
    float* eeb_g    = wsf + WS_EEB_F;
    f16*   cbH      = (f16*)(wsb + WS_CBH_B);
    f16*   cbL      = (f16*)(wsb + WS_CBL_B);

    vq_prep<<<32, 256, 0, stream>>>(emb, wsf, wsu, cbH, cbL, eeb_g);
    vq_main<<<NBLK, 512, 0, stream>>>(x, emb, cbH, cbL, eeb_g, o_out,
                                      idx_out, wsf, wsu + 2, loss_out);
}

// Round 9
// 149.685 us; speedup vs baseline: 1.0631x; 1.0631x over previous
//
#include <hip/hip_runtime.h>

// VQ-VAE quantization. x: [32,64,64,64] fp32, emb: [1024,64] fp32
#define BATCH   32
#define CCH     64
#define HW      4096
#define NPIX    (BATCH * HW)        // 131072
#define KCODES  1024
#define NELEM   (NPIX * CCH)        // 8388608
#define MB      256                 // pixels per block (32 per wave, 2 row-tiles, 8 waves)
#define CK      128                 // codes per LDS chunk (8 chunks, 2x32KB dbuf -> 2 blocks/CU)
#define NBLK    (NPIX / MB)         // 512
#define MARGIN_Q 11u                // ambiguity margin, 1/4096 units (no-LL err ~<=5; 2*5+1)
#define QSCALE   4096.0f            // distance quantization scale
#define QBASE    1048576.0f         // 2^20 baseline; uf stays in (0, 2^22)

typedef _Float16 f16;
typedef __attribute__((ext_vector_type(8))) _Float16 f16x8;
typedef __attribute__((ext_vector_type(4))) float    f32x4;

static __device__ __forceinline__ f32x4 mfma16(f16x8 a, f16x8 b, f32x4 c) {
    return __builtin_amdgcn_mfma_f32_16x16x32_f16(a, b, c, 0, 0, 0);
}

static __device__ __forceinline__ void dma16(void* lds, const void* g) {
    __builtin_amdgcn_global_load_lds(
        (const __attribute__((address_space(1))) unsigned int*)g,
        (__attribute__((address_space(3))) unsigned int*)lds, 16, 0, 0);
}

// median of 3 u32 (v_med3_u32)
static __device__ __forceinline__ unsigned med3u(unsigned a, unsigned b, unsigned c) {
    unsigned d;
    asm("v_med3_u32 %0, %1, %2, %3" : "=v"(d) : "v"(a), "v"(b), "v"(c));
    return d;
}

// ws layout (bytes):
//   [0] f32 loss acc   [8] u32 done-counter (same 64B line as acc)
//   [256..4352)       eeb[k] = 4096*||e_k||^2 + 2^20  (1024 f32)
//   [8192..139264)    cbH swizzled fp16-hi codebook (row r granule g at r*64 + 8*(g^(r&7)))
//   [139264..270336)  cbL fp16-lo, same swizzle
#define WS_EEB_F   64
#define WS_CBH_B   8192
#define WS_CBL_B   139264

__global__ __launch_bounds__(256) void vq_prep(
    const float* __restrict__ emb, float* __restrict__ wsf,
    unsigned* __restrict__ wsu, f16* __restrict__ cbH, f16* __restrict__ cbL,
    float* __restrict__ eeb_g)
{
    const int t   = threadIdx.x;
    const int gid = blockIdx.x * 256 + t;        // 0..8191 granules
    const int row = gid >> 3, gi = gid & 7;
    if (gid == 0) { wsf[0] = 0.f; wsu[2] = 0u; }
    const float* src = emb + (size_t)row * CCH + gi * 8;
    float4 v0 = *(const float4*)(src);
    float4 v1 = *(const float4*)(src + 4);
    float vv[8] = {v0.x, v0.y, v0.z, v0.w, v1.x, v1.y, v1.z, v1.w};
    f16x8 h, l;
    float s = 0.f;
#pragma unroll
    for (int j = 0; j < 8; ++j) {
        f16 hh = (f16)vv[j];
        h[j] = hh;
        l[j] = (f16)(vv[j] - (float)hh);
        s = fmaf(vv[j], vv[j], s);
    }
    const int off = row * 64 + 8 * (gi ^ (row & 7));
    *(f16x8*)(cbH + off) = h;
    *(f16x8*)(cbL + off) = l;
    // ||e||^2: reduce across the 8 granule-threads of this row (adjacent lanes)
    s += __shfl_xor(s, 1, 64);
    s += __shfl_xor(s, 2, 64);
    s += __shfl_xor(s, 4, 64);
    if (gi == 0) eeb_g[row] = fmaf(s, QSCALE, QBASE);
}

// 8 waves x 32 pixels, 2 blocks/CU (L2-resident codebook).
// 6-MFMA H/L product (LL term dropped: RMS contribution ~0.003 units, R3-chain
// empirically exact). Top-3 tracking classifies ambiguous pixels:
//   gap2 >= M: unambiguous.
//   gap2 < M, gap3 >= M: exact fp64 {b1,b2} pair-compare, 1 thread/pixel (parallel).
//   gap3 < M (rare): block-cooperative exact fp64 rescan of all 1024 codes.
__global__ __launch_bounds__(512, 4) void vq_main(
    const float* __restrict__ x,
    const float* __restrict__ emb,
    const f16* __restrict__ cbH, const f16* __restrict__ cbL,
    const float* __restrict__ eeb_g,
    float* __restrict__ o, float* __restrict__ idx_out,
    float* __restrict__ acc, unsigned* __restrict__ done,
    float* __restrict__ loss)
{
    __shared__ __align__(16) char smem[65536];      // 2 x (16K H | 16K L)
    __shared__ float eebl[2][CK];
    __shared__ unsigned bu1[MB], bu2[MB], bu3[MB];
    __shared__ float wred[8];
    __shared__ unsigned short plist[MB], flist[MB];
    __shared__ int np, nf;
    __shared__ __align__(16) float zsh[CCH];
    __shared__ double rbd[8];
    __shared__ int rbi[8];

    const int t    = threadIdx.x;
    const int lane = t & 63;
    const int w    = t >> 6;               // 0..7
    const int col  = lane & 15;
    const int quad = lane >> 4;
    const int c7   = col & 7;
    const int sw0  = 8 * (quad ^ c7);      // swizzled granule offset, chans 0..31
    const int sw1  = sw0 ^ 32;             // chans 32..63
    const int n0   = blockIdx.x * MB;
    const int b    = n0 >> 12;
    const int p0   = n0 & 4095;
    const float* xb = x + (size_t)b * (CCH * HW) + p0;

    // wave w stages its 2KB slice of each 16KB H/L region
    auto stage = [&](int chunk, int bufi) {
        const int k0 = chunk * CK;
        char* lb = smem + bufi * 32768;
        const char* gH = (const char*)cbH + (size_t)k0 * 128 + w * 2048 + lane * 16;
        const char* gL = (const char*)cbL + (size_t)k0 * 128 + w * 2048 + lane * 16;
        char* lH = lb + w * 2048;
        char* lL = lb + 16384 + w * 2048;
        dma16(lH,        gH);
        dma16(lH + 1024, gH + 1024);
        dma16(lL,        gL);
        dma16(lL + 1024, gL + 1024);
        if (t < CK) eebl[bufi][t] = eeb_g[k0 + t];
    };

    stage(0, 0);    // DMA in flight while we build A fragments

    // ---- A fragments straight from global (MFMA A-layout, no LDS trip) ----
    // lane holds pixel (w*32 + rt*16 + col), chans kc*32 + quad*8 + j
    f16x8 aH[2][2], aL[2][2];
#pragma unroll
    for (int rt = 0; rt < 2; ++rt) {
        const int pp = w * 32 + rt * 16 + col;
#pragma unroll
        for (int kc = 0; kc < 2; ++kc) {
            f16x8 h, l;
#pragma unroll
            for (int j = 0; j < 8; ++j) {
                const int c = kc * 32 + quad * 8 + j;
                float zs = -2.0f * xb[(size_t)c * HW + pp];
                f16 hh = (f16)zs;
                h[j] = hh;
                l[j] = (f16)(zs - (float)hh);
            }
            aH[rt][kc] = h;
            aL[rt][kc] = l;
        }
    }

    unsigned best[8], best2[8], best3[8];
#pragma unroll
    for (int s = 0; s < 8; ++s) {
        best[s] = 0xFFFFFFFFu; best2[s] = 0xFFFFFFFFu; best3[s] = 0xFFFFFFFFu;
    }

    const f32x4 zero4 = {0.f, 0.f, 0.f, 0.f};   // persistent C-init quad

    for (int chunk = 0; chunk < KCODES / CK; ++chunk) {
        const int cur = chunk & 1;
        __syncthreads();                        // chunk's DMA visible to all
        if (chunk + 1 < KCODES / CK) stage(chunk + 1, cur ^ 1);

        const f16* bufH = (const f16*)(smem + cur * 32768);
        const f16* bufL = bufH + 8192;          // +16384 bytes
        const int k0 = chunk * CK;

#pragma unroll
        for (int tile = 0; tile < CK / 16; ++tile) {
            const f16* bh = bufH + (tile * 16 + col) * 64;
            const f16* bl = bufL + (tile * 16 + col) * 64;
            f16x8 bH0 = *(const f16x8*)(bh + sw0);
            f16x8 bH1 = *(const f16x8*)(bh + sw1);
            f16x8 bL0 = *(const f16x8*)(bl + sw0);
            f16x8 bL1 = *(const f16x8*)(bl + sw1);
            const float eebc = eebl[cur][tile * 16 + col];
            const unsigned kb = (unsigned)(k0 + tile * 16 + col);
#pragma unroll
            for (int rt = 0; rt < 2; ++rt) {
                // two independent 3-deep MFMA chains (HH + HL cross terms; LL dropped)
                f32x4 u = mfma16(aH[rt][0], bH0, zero4);
                f32x4 v = mfma16(aH[rt][1], bH1, zero4);
                u = mfma16(aL[rt][0], bH0, u);
                v = mfma16(aL[rt][1], bH1, v);
                u = mfma16(aH[rt][0], bL0, u);
                v = mfma16(aH[rt][1], bL1, v);
#pragma unroll
                for (int r = 0; r < 4; ++r) {
                    float uf = fmaf(u[r] + v[r], QSCALE, eebc);   // in (0, 2^22)
                    unsigned pk = (((unsigned)uf) << 10) | kb;
                    const int s = rt * 4 + r;
                    const unsigned b1 = best[s], b2 = best2[s];
                    best3[s] = med3u(b2, best3[s], pk);  // 3rd-best insert (uses old b2)
                    best2[s] = med3u(b1, b2, pk);        // 2nd-best insert
                    best[s]  = min(b1, pk);
                }
            }
        }
    }

    // ---- cross-lane sorted-top-3 merge over the 16 code-columns ----
#pragma unroll
    for (int d = 1; d < 16; d <<= 1) {
#pragma unroll
        for (int s = 0; s < 8; ++s) {
            unsigned o1 = __shfl_xor(best[s],  d, 64);
            unsigned o2 = __shfl_xor(best2[s], d, 64);
            unsigned o3 = __shfl_xor(best3[s], d, 64);
            unsigned m1 = max(best[s], o1);
            unsigned n2 = min(best2[s], o2);
            unsigned x2 = max(best2[s], o2);
            unsigned n3 = min(best3[s], o3);
            best3[s] = min(min(max(m1, n2), x2), n3);
            best2[s] = min(m1, n2);
            best[s]  = min(best[s], o1);
        }
    }
    if (t == 0) { np = 0; nf = 0; }
    if (col == 0) {
#pragma unroll
        for (int rt = 0; rt < 2; ++rt)
#pragma unroll
            for (int r = 0; r < 4; ++r) {
                const int pl = w * 32 + rt * 16 + quad * 4 + r;   // C/D row map
                bu1[pl] = best[rt * 4 + r];
                bu2[pl] = best2[rt * 4 + r];
                bu3[pl] = best3[rt * 4 + r];
            }
    }
    __syncthreads();

    // ---- classify ambiguous pixels ----
    if (t < MB) {
        const unsigned q1 = bu1[t] >> 10;
        if ((bu2[t] >> 10) - q1 < MARGIN_Q) {
            if ((bu3[t] >> 10) - q1 < MARGIN_Q) {
                flist[atomicAdd(&nf, 1)] = (unsigned short)t;   // rare: full rescan
            } else {
                plist[atomicAdd(&np, 1)] = (unsigned short)t;   // common: pair-compare
            }
        }
    }
    __syncthreads();

    // ---- pair path: one thread per pixel, exact fp64 over {b1, b2} only ----
    if (t < np) {
        const int pix = plist[t];
        const unsigned k1 = bu1[pix] & 1023u, k2 = bu2[pix] & 1023u;
        const float* e1 = emb + (size_t)k1 * CCH;
        const float* e2 = emb + (size_t)k2 * CCH;
        const float* xp = xb + pix;
        double d1 = 0.0, d2 = 0.0;
#pragma unroll 1
        for (int c = 0; c < CCH; c += 4) {
            float4 a4 = *(const float4*)(e1 + c);
            float4 b4 = *(const float4*)(e2 + c);
            float xv0 = xp[(size_t)(c + 0) * HW];
            float xv1 = xp[(size_t)(c + 1) * HW];
            float xv2 = xp[(size_t)(c + 2) * HW];
            float xv3 = xp[(size_t)(c + 3) * HW];
            double ta0 = (double)xv0 - (double)a4.x, tb0 = (double)xv0 - (double)b4.x;
            double ta1 = (double)xv1 - (double)a4.y, tb1 = (double)xv1 - (double)b4.y;
            double ta2 = (double)xv2 - (double)a4.z, tb2 = (double)xv2 - (double)b4.z;
            double ta3 = (double)xv3 - (double)a4.w, tb3 = (double)xv3 - (double)b4.w;
            d1 = fma(ta0, ta0, fma(ta1, ta1, fma(ta2, ta2, fma(ta3, ta3, d1))));
            d2 = fma(tb0, tb0, fma(tb1, tb1, fma(tb2, tb2, fma(tb3, tb3, d2))));
        }
        const unsigned kw = (d2 < d1 || (d2 == d1 && k2 < k1)) ? k2 : k1;
        bu1[pix] = kw;
    }

    // ---- full-rescan path (rare): block-cooperative exact fp64 over 1024 codes ----
    const int nfl = nf;
    for (int i = 0; i < nfl; ++i) {
        const int pix = flist[i];
        __syncthreads();
        if (t < CCH) zsh[t] = xb[(size_t)t * HW + pix];
        __syncthreads();
        double bd = 1e300; int bi = KCODES;
#pragma unroll 1
        for (int j = 0; j < 2; ++j) {
            const int k = t + j * 512;
            const float4* er4 = (const float4*)(emb + (size_t)k * CCH);
            const float4* zs4 = (const float4*)zsh;
            double d = 0.0;
#pragma unroll 1
            for (int c = 0; c < 16; ++c) {
                float4 ev = er4[c];
                float4 zv = zs4[c];
                double t0 = (double)zv.x - (double)ev.x;
                double t1 = (double)zv.y - (double)ev.y;
                double t2 = (double)zv.z - (double)ev.z;
                double t3 = (double)zv.w - (double)ev.w;
                d = fma(t0, t0, fma(t1, t1, fma(t2, t2, fma(t3, t3, d))));
            }
            if (d < bd) { bd = d; bi = k; }     // k ascending: strict < keeps lowest idx
        }
#pragma unroll 1
        for (int dlt = 1; dlt < 64; dlt <<= 1) {
            double od = __shfl_xor(bd, dlt, 64);
            int    oi = __shfl_xor(bi, dlt, 64);
            if (od < bd || (od == bd && oi < bi)) { bd = od; bi = oi; }
        }
        if (lane == 0) { rbd[w] = bd; rbi[w] = bi; }
        __syncthreads();
        if (t == 0) {
            double fb = rbd[0]; int fi = rbi[0];
            for (int q = 1; q < 8; ++q)
                if (rbd[q] < fb || (rbd[q] == fb && rbi[q] < fi)) { fb = rbd[q]; fi = rbi[q]; }
            bu1[pix] = (unsigned)fi;
        }
    }
    __syncthreads();   // pair/full bu1 updates visible to epilogue

    // ---- epilogue: 512 threads over 256 pixels x 64 chans (half each) ----
    const int pix  = t & 255;
    const int half = t >> 8;               // 0: chans 0..31, 1: chans 32..63
    const unsigned bidx = bu1[pix] & 1023u;
    if (half == 0) {
        idx_out[n0 + pix] = (float)bidx;
    }
    float ss = 0.f;
    {
        const float4* er4 = (const float4*)(emb + (size_t)bidx * CCH) + half * 8;
        const float* xbt = xb + pix;
        float* ob = o + (size_t)b * (CCH * HW) + p0 + pix;
#pragma unroll
        for (int i = 0; i < 8; ++i) {
            float4 ev = er4[i];
            float evv[4] = {ev.x, ev.y, ev.z, ev.w};
#pragma unroll
            for (int q = 0; q < 4; ++q) {
                const int c = half * 32 + i * 4 + q;
                float xv = xbt[(size_t)c * HW];
                float e  = evv[q];
                ob[(size_t)c * HW] = xv + (e - xv);
                float d = xv - e;
                ss = fmaf(d, d, ss);
            }
        }
    }
    for (int off = 32; off; off >>= 1) ss += __shfl_down(ss, off, 64);
    if (lane == 0) wred[w] = ss;
    __syncthreads();
    if (t == 0) {
        float s2 = 0.f;
#pragma unroll
        for (int q = 0; q < 8; ++q) s2 += wred[q];
        // fused finalization, fence-free (R7-proven):
        float old = atomicAdd(acc, s2);               // device-scope, returns -> vmcnt wait
        asm volatile("" : : "v"(old));                // consume: acc-add applied at L2 here
        unsigned prev = atomicAdd(done, 1u);          // same 64B line as acc -> serialized
        if (prev == (unsigned)(NBLK - 1)) {
            float a = atomicAdd(acc, 0.0f);           // complete sum
            *loss = 1.25f * a * (1.0f / (float)NELEM);
        }
    }
}

extern "C" void kernel_launch(void* const* d_in, const int* in_sizes, int n_in,
                              void* d_out, int out_size, void* d_ws, size_t ws_size,
                              hipStream_t stream) {
    const float* x   = (const float*)d_in[0];
    const float* emb = (const float*)d_in[1];
    float*    out = (float*)d_out;
    float*    wsf = (float*)d_ws;
    unsigned* wsu = (unsigned*)d_ws;
    char*     wsb = (char*)d_ws;

    float* o_out    = out;
    float* loss_out = out + NELEM;
    float* idx_out  = out + NELEM + 1;
    float* eeb_g    = wsf + WS_EEB_F;
    f16*   cbH      = (f16*)(wsb + WS_CBH_B);
    f16*   cbL      = (f16*)(wsb + WS_CBL_B);

    vq_prep<<<32, 256, 0, stream>>>(emb, wsf, wsu, cbH, cbL, eeb_g);
    vq_main<<<NBLK, 512, 0, stream>>>(x, emb, cbH, cbL, eeb_g, o_out,
                                      idx_out, wsf, wsu + 2, loss_out);
}